// Round 2
// baseline (433.349 us; speedup 1.0000x reference)
//
#include <hip/hip_runtime.h>
#include <hip/hip_bf16.h>
#include <stdint.h>

typedef _Float16 f16;
typedef _Float16 f16x4 __attribute__((ext_vector_type(4)));
typedef _Float16 f16x8 __attribute__((ext_vector_type(8)));
typedef float f32x4 __attribute__((ext_vector_type(4)));

// async global->LDS copy, 16B per lane. LDS dest must be wave-uniform-base + lane*16.
#define ASYNC_COPY16(gsrc, ldst)                                                   \
    __builtin_amdgcn_global_load_lds(                                              \
        (__attribute__((address_space(1))) void*)(gsrc),                           \
        (__attribute__((address_space(3))) void*)(ldst), 16, 0, 0)

// ---------------------------------------------------------------------------
// fp32 -> f16 conversion, 4 elems/thread (float4 load, 8B store)
// ---------------------------------------------------------------------------
__global__ __launch_bounds__(256) void cvt_f32_to_f16(const float* __restrict__ in,
                                                      f16* __restrict__ out, int n4) {
    int i = blockIdx.x * 256 + threadIdx.x;
    if (i >= n4) return;
    float4 v = ((const float4*)in)[i];
    f16x4 o;
    o.x = (f16)v.x; o.y = (f16)v.y; o.z = (f16)v.z; o.w = (f16)v.w;
    ((f16x4*)out)[i] = o;
}

// three conversions in one launch: y -> yb, W1 -> w1b, W2 -> w2b
__global__ __launch_bounds__(256) void cvt3_f32_to_f16(const float* __restrict__ y,
                                                       const float* __restrict__ W1,
                                                       const float* __restrict__ W2,
                                                       f16* __restrict__ yb,
                                                       f16* __restrict__ w1b,
                                                       f16* __restrict__ w2b,
                                                       int nY4, int nW4) {
    int i = blockIdx.x * 256 + threadIdx.x;
    const float* src;
    f16* dst;
    int off;
    if (i < nY4) {
        src = y; dst = yb; off = i;
    } else if (i < nY4 + nW4) {
        src = W1; dst = w1b; off = i - nY4;
    } else {
        src = W2; dst = w2b; off = i - nY4 - nW4;
        if (off >= nW4) return;
    }
    float4 v = ((const float4*)src)[off];
    f16x4 o;
    o.x = (f16)v.x; o.y = (f16)v.y; o.z = (f16)v.z; o.w = (f16)v.w;
    ((f16x4*)dst)[off] = o;
}

// ---------------------------------------------------------------------------
// C = A(MxK) * B(NxK)^T + bias, f16 inputs, fp32 accumulate.
// Tile 128(M) x 64(N), BK=32. 128 threads = 2 waves; wave w computes rows
// [w*64, w*64+64) x all 64 cols as a 4x4 grid of 16x16x32 MFMAs (identical
// per-wave shape to the m97 structure). Grid = (N/64, M/128): 2x the blocks
// of the 128x128 tiling -> 4 blocks/CU at this problem size, so barrier
// drains in one block overlap with MFMA in the other three.
// STORE_F16: 1 -> store f16 (for h), 0 -> store fp32 (for out).
// ---------------------------------------------------------------------------
template <int STORE_F16>
__global__ __launch_bounds__(128) void gemm_bt(const f16* __restrict__ A,
                                               const f16* __restrict__ Bm,
                                               const float* __restrict__ bias,
                                               void* __restrict__ Cout,
                                               int M, int N, int K) {
    constexpr int BM = 128, BN = 64, BK = 32;
    __shared__ __align__(16) f16 sA[BM * BK];  // 8 KB
    __shared__ __align__(16) f16 sB[BN * BK];  // 4 KB

    const int tid  = threadIdx.x;
    const int lane = tid & 63;
    const int wave = tid >> 6;  // 0..1, M-direction

    const int bm = blockIdx.y * BM;
    const int bn = blockIdx.x * BN;

    // staging map: thread t covers 16B segment (row = t>>2, seg = t&3) and
    // +32-row repeats. LDS row-major [rows][32] f16 unpadded: per instruction,
    // wave-lane LDS offsets are base + lane*16 as required by global_load_lds.
    const int srow = tid >> 2;        // 0..31
    const int scol = (tid & 3) * 8;   // in halves; *2 = bytes 0/16/32/48

    const f16* Aptr = A + (size_t)bm * K;
    const f16* Bptr = Bm + (size_t)bn * K;

    f32x4 acc[4][4] = {};

    const int quad = lane >> 4;
    const int l16  = lane & 15;

    for (int k0 = 0; k0 < K; k0 += BK) {
#pragma unroll
        for (int i = 0; i < 4; i++) {
            const int r = srow + 32 * i;
            ASYNC_COPY16(Aptr + (size_t)r * K + k0 + scol, &sA[r * BK + scol]);
        }
#pragma unroll
        for (int j = 0; j < 2; j++) {
            const int r = srow + 32 * j;
            ASYNC_COPY16(Bptr + (size_t)r * K + k0 + scol, &sB[r * BK + scol]);
        }
        __syncthreads();  // drains vmcnt (global_load_lds) + barrier

        f16x8 af[4], bf[4];
#pragma unroll
        for (int mi = 0; mi < 4; mi++)
            af[mi] = *(const f16x8*)&sA[(wave * 64 + mi * 16 + l16) * BK + quad * 8];
#pragma unroll
        for (int ni = 0; ni < 4; ni++)
            bf[ni] = *(const f16x8*)&sB[(ni * 16 + l16) * BK + quad * 8];

#pragma unroll
        for (int mi = 0; mi < 4; mi++)
#pragma unroll
            for (int ni = 0; ni < 4; ni++)
                acc[mi][ni] = __builtin_amdgcn_mfma_f32_16x16x32_f16(af[mi], bf[ni],
                                                                     acc[mi][ni], 0, 0, 0);
        __syncthreads();  // protect LDS before next stage
    }

    // epilogue: C/D layout col = lane&15, row = quad*4 + reg
#pragma unroll
    for (int ni = 0; ni < 4; ni++) {
        const int col = bn + ni * 16 + l16;
        const float bv = bias[col];
#pragma unroll
        for (int mi = 0; mi < 4; mi++) {
            const int row0 = bm + wave * 64 + mi * 16 + quad * 4;
#pragma unroll
            for (int r = 0; r < 4; r++) {
                float v = acc[mi][ni][r] + bv;
                if (STORE_F16)
                    ((f16*)Cout)[(size_t)(row0 + r) * N + col] = (f16)v;
                else
                    ((float*)Cout)[(size_t)(row0 + r) * N + col] = v;
            }
        }
    }
}

// ---------------------------------------------------------------------------
// replicator: per row r, dot = sum_k y*out; out = y*(out - dot). In-place on out.
// one block (256 thr) per row, float4 loads. Second pass hits L2.
// ---------------------------------------------------------------------------
__global__ __launch_bounds__(256) void replicator(const float* __restrict__ y,
                                                  float* __restrict__ out, int N) {
    const int row = blockIdx.x;
    const float4* y4 = (const float4*)(y + (size_t)row * N);
    float4* o4 = (float4*)(out + (size_t)row * N);
    const int n4 = N / 4;

    float p = 0.f;
    for (int i = threadIdx.x; i < n4; i += 256) {
        float4 a = y4[i], b = o4[i];
        p += a.x * b.x + a.y * b.y + a.z * b.z + a.w * b.w;
    }
#pragma unroll
    for (int off = 32; off > 0; off >>= 1) p += __shfl_down(p, off, 64);

    __shared__ float sred[4];
    if ((threadIdx.x & 63) == 0) sred[threadIdx.x >> 6] = p;
    __syncthreads();
    const float dot = sred[0] + sred[1] + sred[2] + sred[3];

    for (int i = threadIdx.x; i < n4; i += 256) {
        float4 a = y4[i], b = o4[i];
        float4 r;
        r.x = a.x * (b.x - dot);
        r.y = a.y * (b.y - dot);
        r.z = a.z * (b.z - dot);
        r.w = a.w * (b.w - dot);
        o4[i] = r;
    }
}

extern "C" void kernel_launch(void* const* d_in, const int* in_sizes, int n_in,
                              void* d_out, int out_size, void* d_ws, size_t ws_size,
                              hipStream_t stream) {
    // inputs: 0=t(1), 1=y(B*N), 2=W1(N*N), 3=b1(N), 4=W2(N*N), 5=b2(N)
    const float* y  = (const float*)d_in[1];
    const float* W1 = (const float*)d_in[2];
    const float* b1 = (const float*)d_in[3];
    const float* W2 = (const float*)d_in[4];
    const float* b2 = (const float*)d_in[5];

    const int N = in_sizes[3];            // 4096
    const int B = in_sizes[1] / N;        // 2048
    float* out = (float*)d_out;

    const size_t szY = (size_t)B * N;     // elements
    const size_t szW = (size_t)N * N;

    const int yn4 = (int)(szY / 4);
    const int wn4 = (int)(szW / 4);

    dim3 g1(N / 64, B / 128);             // 1024 blocks

    const size_t need_big = (szY + 2 * szW + szY) * sizeof(f16);  // yb|w1b|w2b|hb

    if (ws_size >= need_big) {
        // workspace: yb | w1b | w2b | hb  — all converts in one launch
        f16* yb  = (f16*)d_ws;
        f16* w1b = yb + szY;
        f16* w2b = w1b + szW;
        f16* hb  = w2b + szW;

        const int tot4 = yn4 + 2 * wn4;
        cvt3_f32_to_f16<<<(tot4 + 255) / 256, 256, 0, stream>>>(y, W1, W2, yb, w1b, w2b,
                                                                yn4, wn4);
        gemm_bt<1><<<g1, 128, 0, stream>>>(yb, w1b, b1, hb, B, N, N);
        gemm_bt<0><<<g1, 128, 0, stream>>>(hb, w2b, b2, out, B, N, N);
    } else {
        // fallback: reuse one weight buffer (yb | wb | hb)
        f16* yb = (f16*)d_ws;
        f16* wb = yb + szY;
        f16* hb = wb + szW;

        cvt_f32_to_f16<<<yn4 / 256, 256, 0, stream>>>(y, yb, yn4);
        cvt_f32_to_f16<<<wn4 / 256, 256, 0, stream>>>(W1, wb, wn4);
        gemm_bt<1><<<g1, 128, 0, stream>>>(yb, wb, b1, hb, B, N, N);
        cvt_f32_to_f16<<<wn4 / 256, 256, 0, stream>>>(W2, wb, wn4);
        gemm_bt<0><<<g1, 128, 0, stream>>>(hb, wb, b2, out, B, N, N);
    }

    replicator<<<B, 256, 0, stream>>>(y, out, N);
}

// Round 3
// 349.015 us; speedup vs baseline: 1.2416x; 1.2416x over previous
//
#include <hip/hip_runtime.h>
#include <hip/hip_bf16.h>
#include <stdint.h>

typedef _Float16 f16;
typedef _Float16 f16x4 __attribute__((ext_vector_type(4)));
typedef _Float16 f16x8 __attribute__((ext_vector_type(8)));
typedef float f32x4 __attribute__((ext_vector_type(4)));

// async global->LDS copy, 16B per lane. LDS dest must be wave-uniform-base + lane*16.
#define ASYNC_COPY16(gsrc, ldst)                                                   \
    __builtin_amdgcn_global_load_lds(                                              \
        (__attribute__((address_space(1))) void*)(gsrc),                           \
        (__attribute__((address_space(3))) void*)(ldst), 16, 0, 0)

// ---------------------------------------------------------------------------
// fp32 -> f16 conversion, 4 elems/thread (float4 load, 8B store)
// ---------------------------------------------------------------------------
__global__ __launch_bounds__(256) void cvt_f32_to_f16(const float* __restrict__ in,
                                                      f16* __restrict__ out, int n4) {
    int i = blockIdx.x * 256 + threadIdx.x;
    if (i >= n4) return;
    float4 v = ((const float4*)in)[i];
    f16x4 o;
    o.x = (f16)v.x; o.y = (f16)v.y; o.z = (f16)v.z; o.w = (f16)v.w;
    ((f16x4*)out)[i] = o;
}

// three conversions in one launch: y -> yb, W1 -> w1b, W2 -> w2b
__global__ __launch_bounds__(256) void cvt3_f32_to_f16(const float* __restrict__ y,
                                                       const float* __restrict__ W1,
                                                       const float* __restrict__ W2,
                                                       f16* __restrict__ yb,
                                                       f16* __restrict__ w1b,
                                                       f16* __restrict__ w2b,
                                                       int nY4, int nW4) {
    int i = blockIdx.x * 256 + threadIdx.x;
    const float* src;
    f16* dst;
    int off;
    if (i < nY4) {
        src = y; dst = yb; off = i;
    } else if (i < nY4 + nW4) {
        src = W1; dst = w1b; off = i - nY4;
    } else {
        src = W2; dst = w2b; off = i - nY4 - nW4;
        if (off >= nW4) return;
    }
    float4 v = ((const float4*)src)[off];
    f16x4 o;
    o.x = (f16)v.x; o.y = (f16)v.y; o.z = (f16)v.z; o.w = (f16)v.w;
    ((f16x4*)dst)[off] = o;
}

// ---------------------------------------------------------------------------
// C = A(MxK) * B(NxK)^T + bias, f16 in, fp32 accumulate.
// Tile 128x128, 256 thr = 4 waves (2x2), each wave 64x64 as 4x4 16x16x32 MFMAs.
// BK=64, double-buffered LDS (64 KB), ONE barrier per K-iter:
//   barrier (drains prefetch issued last iter) -> issue prefetch(next, buf^1)
//   -> compute(cur buf). Prefetch latency is hidden behind 32 MFMAs/wave.
// LDS rows are 128 B; XOR swizzle (seg ^= row&7) applied on the GLOBAL source
// (global_load_lds forces linear LDS writes) and undone at ds_read, so
// consecutive l16 lanes hit distinct bank-quads (2-way floor, free).
// STORE_F16: 1 -> f16 output (h), 0 -> fp32 output.
// ---------------------------------------------------------------------------
template <int STORE_F16>
__global__ __launch_bounds__(256) void gemm_bt(const f16* __restrict__ A,
                                               const f16* __restrict__ Bm,
                                               const float* __restrict__ bias,
                                               void* __restrict__ Cout,
                                               int M, int N, int K) {
    constexpr int BM = 128, BN = 128, BK = 64;
    __shared__ __align__(16) f16 sA[2][BM * BK];  // 2 x 16 KB
    __shared__ __align__(16) f16 sB[2][BN * BK];  // 2 x 16 KB

    const int tid   = threadIdx.x;
    const int lane  = tid & 63;
    const int wave  = tid >> 6;   // 0..3
    const int waveM = wave >> 1;  // 0..1
    const int waveN = wave & 1;   // 0..1

    const int bm = blockIdx.y * BM;
    const int bn = blockIdx.x * BN;

    const f16* Aptr = A + (size_t)bm * K;
    const f16* Bptr = Bm + (size_t)bn * K;

    // staging: 16 KB per matrix per stage = 4 chunks of 4 KB; chunk j covers
    // rows [j*32, j*32+32). Thread t writes LDS halves [j*2048 + t*8, +8)
    // (linear; per wave that's wavebase + lane*16 bytes as required).
    // Global segment fetched is XOR-swizzled: seg = (t&7) ^ (row&7).
    const int srow_lo = tid >> 3;        // 0..31 within chunk
    const int sseg    = tid & 7;         // 16B segment 0..7

    f32x4 acc[4][4] = {};

    const int quad = lane >> 4;
    const int l16  = lane & 15;

    const int iters = K / BK;

    // ---- prologue: stage iter 0 into buf 0
    {
#pragma unroll
        for (int j = 0; j < 4; j++) {
            const int row = j * 32 + srow_lo;
            const int seg = sseg ^ (row & 7);
            ASYNC_COPY16(Aptr + (size_t)row * K + 0 + seg * 8, &sA[0][j * 2048 + tid * 8]);
        }
#pragma unroll
        for (int j = 0; j < 4; j++) {
            const int row = j * 32 + srow_lo;
            const int seg = sseg ^ (row & 7);
            ASYNC_COPY16(Bptr + (size_t)row * K + 0 + seg * 8, &sB[0][j * 2048 + tid * 8]);
        }
    }

    int cur = 0;
    for (int it = 0; it < iters; ++it) {
        __syncthreads();  // drains vmcnt(0): buf[cur] is ready

        // prefetch next tile into buf[cur^1] (in flight during compute below)
        if (it + 1 < iters) {
            const int k0 = (it + 1) * BK;
#pragma unroll
            for (int j = 0; j < 4; j++) {
                const int row = j * 32 + srow_lo;
                const int seg = sseg ^ (row & 7);
                ASYNC_COPY16(Aptr + (size_t)row * K + k0 + seg * 8,
                             &sA[cur ^ 1][j * 2048 + tid * 8]);
            }
#pragma unroll
            for (int j = 0; j < 4; j++) {
                const int row = j * 32 + srow_lo;
                const int seg = sseg ^ (row & 7);
                ASYNC_COPY16(Bptr + (size_t)row * K + k0 + seg * 8,
                             &sB[cur ^ 1][j * 2048 + tid * 8]);
            }
        }

        // compute from buf[cur]: 2 k-halves of 32, 16 MFMAs each
#pragma unroll
        for (int h = 0; h < 2; h++) {
            f16x8 af[4], bf[4];
#pragma unroll
            for (int mi = 0; mi < 4; mi++) {
                const int row = waveM * 64 + mi * 16 + l16;
                const int seg = (h * 4 + quad) ^ (row & 7);
                af[mi] = *(const f16x8*)&sA[cur][row * BK + seg * 8];
            }
#pragma unroll
            for (int ni = 0; ni < 4; ni++) {
                const int row = waveN * 64 + ni * 16 + l16;
                const int seg = (h * 4 + quad) ^ (row & 7);
                bf[ni] = *(const f16x8*)&sB[cur][row * BK + seg * 8];
            }
#pragma unroll
            for (int mi = 0; mi < 4; mi++)
#pragma unroll
                for (int ni = 0; ni < 4; ni++)
                    acc[mi][ni] = __builtin_amdgcn_mfma_f32_16x16x32_f16(af[mi], bf[ni],
                                                                         acc[mi][ni], 0, 0, 0);
        }
        cur ^= 1;
        // NOTE: no second barrier. The next iteration's barrier (lgkmcnt(0))
        // guarantees all ds_reads of buf[cur] completed before any wave's
        // subsequent prefetch overwrites it.
    }

    // epilogue: C/D layout col = lane&15, row = quad*4 + reg
#pragma unroll
    for (int ni = 0; ni < 4; ni++) {
        const int col = bn + waveN * 64 + ni * 16 + l16;
        const float bv = bias[col];
#pragma unroll
        for (int mi = 0; mi < 4; mi++) {
            const int row0 = bm + waveM * 64 + mi * 16 + quad * 4;
#pragma unroll
            for (int r = 0; r < 4; r++) {
                float v = acc[mi][ni][r] + bv;
                if (STORE_F16)
                    ((f16*)Cout)[(size_t)(row0 + r) * N + col] = (f16)v;
                else
                    ((float*)Cout)[(size_t)(row0 + r) * N + col] = v;
            }
        }
    }
}

// ---------------------------------------------------------------------------
// replicator: per row r, dot = sum_k y*out; out = y*(out - dot). In-place.
// one block (256 thr) per row, float4 loads; second pass mostly L2-hits.
// ---------------------------------------------------------------------------
__global__ __launch_bounds__(256) void replicator(const float* __restrict__ y,
                                                  float* __restrict__ out, int N) {
    const int row = blockIdx.x;
    const float4* y4 = (const float4*)(y + (size_t)row * N);
    float4* o4 = (float4*)(out + (size_t)row * N);
    const int n4 = N / 4;

    float p = 0.f;
    for (int i = threadIdx.x; i < n4; i += 256) {
        float4 a = y4[i], b = o4[i];
        p += a.x * b.x + a.y * b.y + a.z * b.z + a.w * b.w;
    }
#pragma unroll
    for (int off = 32; off > 0; off >>= 1) p += __shfl_down(p, off, 64);

    __shared__ float sred[4];
    if ((threadIdx.x & 63) == 0) sred[threadIdx.x >> 6] = p;
    __syncthreads();
    const float dot = sred[0] + sred[1] + sred[2] + sred[3];

    for (int i = threadIdx.x; i < n4; i += 256) {
        float4 a = y4[i], b = o4[i];
        float4 r;
        r.x = a.x * (b.x - dot);
        r.y = a.y * (b.y - dot);
        r.z = a.z * (b.z - dot);
        r.w = a.w * (b.w - dot);
        o4[i] = r;
    }
}

extern "C" void kernel_launch(void* const* d_in, const int* in_sizes, int n_in,
                              void* d_out, int out_size, void* d_ws, size_t ws_size,
                              hipStream_t stream) {
    // inputs: 0=t(1), 1=y(B*N), 2=W1(N*N), 3=b1(N), 4=W2(N*N), 5=b2(N)
    const float* y  = (const float*)d_in[1];
    const float* W1 = (const float*)d_in[2];
    const float* b1 = (const float*)d_in[3];
    const float* W2 = (const float*)d_in[4];
    const float* b2 = (const float*)d_in[5];

    const int N = in_sizes[3];            // 4096
    const int B = in_sizes[1] / N;        // 2048
    float* out = (float*)d_out;

    const size_t szY = (size_t)B * N;     // elements
    const size_t szW = (size_t)N * N;

    const int yn4 = (int)(szY / 4);
    const int wn4 = (int)(szW / 4);

    dim3 g1(N / 128, B / 128);            // 512 blocks, 4 waves each

    const size_t need_big = (szY + 2 * szW + szY) * sizeof(f16);  // yb|w1b|w2b|hb

    if (ws_size >= need_big) {
        f16* yb  = (f16*)d_ws;
        f16* w1b = yb + szY;
        f16* w2b = w1b + szW;
        f16* hb  = w2b + szW;

        const int tot4 = yn4 + 2 * wn4;
        cvt3_f32_to_f16<<<(tot4 + 255) / 256, 256, 0, stream>>>(y, W1, W2, yb, w1b, w2b,
                                                                yn4, wn4);
        gemm_bt<1><<<g1, 256, 0, stream>>>(yb, w1b, b1, hb, B, N, N);
        gemm_bt<0><<<g1, 256, 0, stream>>>(hb, w2b, b2, out, B, N, N);
    } else {
        // fallback: reuse one weight buffer (yb | wb | hb)
        f16* yb = (f16*)d_ws;
        f16* wb = yb + szY;
        f16* hb = wb + szW;

        cvt_f32_to_f16<<<yn4 / 256, 256, 0, stream>>>(y, yb, yn4);
        cvt_f32_to_f16<<<wn4 / 256, 256, 0, stream>>>(W1, wb, wn4);
        gemm_bt<1><<<g1, 256, 0, stream>>>(yb, wb, b1, hb, B, N, N);
        cvt_f32_to_f16<<<wn4 / 256, 256, 0, stream>>>(W2, wb, wn4);
        gemm_bt<0><<<g1, 256, 0, stream>>>(hb, wb, b2, out, B, N, N);
    }

    replicator<<<B, 256, 0, stream>>>(y, out, N);
}